// Round 4
// baseline (716.137 us; speedup 1.0000x reference)
//
#include <hip/hip_runtime.h>
#include <math.h>

#define N0 32768
#define N1 8192
#define N2 2048
#define E0 262144
#define E1 65536
#define E2 16384
#define NTOT (N0+N1+N2)     // 43008 (multiple of 256)
#define ETOT (E0+E1+E2)     // 344064
#define NBLK (NTOT/256)     // 168
#define EPS 1e-9f

static inline int cdiv(int a, int b){ return (a + b - 1) / b; }

// ---------------- small utility kernels ----------------
__global__ void k_gather_pos(const float* __restrict__ pos, const int* __restrict__ idx,
                             float* __restrict__ out, int n){
  int i = blockIdx.x*256 + threadIdx.x;
  if (i < n){
    int s = idx[i];
    out[i*3+0] = pos[s*3+0];
    out[i*3+1] = pos[s*3+1];
    out[i*3+2] = pos[s*3+2];
  }
}

// ---------------- concatenated CSR build ----------------
// node index space: [0,N0) level0 | [N0,N0+N1) level1 | rest level2
// edge payload space: [0,E0) | [E0,E0+E1) | rest  (global CSR offsets)
__global__ void k_countA(const int* __restrict__ d0, const int* __restrict__ d1,
                         const int* __restrict__ d2, int* cnt){
  int e = blockIdx.x*256 + threadIdx.x;
  if (e < E0)            atomicAdd(&cnt[d0[e]], 1);
  else if (e < E0+E1)    atomicAdd(&cnt[N0 + d1[e-E0]], 1);
  else if (e < ETOT)     atomicAdd(&cnt[N0+N1 + d2[e-E0-E1]], 1);
}
__global__ __launch_bounds__(256) void k_scan1(const int* __restrict__ cnt,
                                               int* __restrict__ excl,
                                               int* __restrict__ bsum){
  __shared__ int lds[256];
  int tid = threadIdx.x;
  int i = blockIdx.x*256 + tid;
  int v = cnt[i];
  lds[tid] = v;
  __syncthreads();
  for (int off = 1; off < 256; off <<= 1){
    int t = (tid >= off) ? lds[tid - off] : 0;
    __syncthreads();
    lds[tid] += t;
    __syncthreads();
  }
  excl[i] = lds[tid] - v;
  if (tid == 255) bsum[blockIdx.x] = lds[255];
}
__global__ __launch_bounds__(256) void k_scan2(int* bsum, int nb){
  __shared__ int lds[256];
  int tid = threadIdx.x;
  int v = (tid < nb) ? bsum[tid] : 0;
  lds[tid] = v;
  __syncthreads();
  for (int off = 1; off < 256; off <<= 1){
    int t = (tid >= off) ? lds[tid - off] : 0;
    __syncthreads();
    lds[tid] += t;
    __syncthreads();
  }
  if (tid < nb) bsum[tid] = lds[tid] - v;
}
__global__ __launch_bounds__(256) void k_scan3(const int* __restrict__ excl,
                                               const int* __restrict__ bsum,
                                               int* __restrict__ row,
                                               int* __restrict__ cur){
  int i = blockIdx.x*256 + threadIdx.x;
  int r = excl[i] + bsum[blockIdx.x];
  row[i] = r; cur[i] = r;
  if (i == 0) row[NTOT] = ETOT;
}
// scatter edge payload (src-local-id, r, rel) into global CSR order; geometry fused
__global__ void k_scatter_geoA(const int* __restrict__ s0, const int* __restrict__ d0,
                               const int* __restrict__ s1, const int* __restrict__ d1,
                               const int* __restrict__ s2, const int* __restrict__ d2,
                               const float* __restrict__ pos0, const float* __restrict__ pos1,
                               const float* __restrict__ pos2, int* cur,
                               int* __restrict__ srcs, float* __restrict__ rG,
                               float* __restrict__ relG){
  int e = blockIdx.x*256 + threadIdx.x;
  if (e >= ETOT) return;
  int s, d, noff; const float* pos;
  if (e < E0)        { s = s0[e];        d = d0[e];        pos = pos0; noff = 0; }
  else if (e < E0+E1){ s = s1[e-E0];     d = d1[e-E0];     pos = pos1; noff = N0; }
  else               { s = s2[e-E0-E1];  d = d2[e-E0-E1];  pos = pos2; noff = N0+N1; }
  float dx = pos[d*3+0]-pos[s*3+0];
  float dy = pos[d*3+1]-pos[s*3+1];
  float dz = pos[d*3+2]-pos[s*3+2];
  int p = atomicAdd(&cur[noff + d], 1);
  srcs[p] = s;
  rG[p] = sqrtf(dx*dx+dy*dy+dz*dz+1e-12f);
  relG[p*3+0]=dx; relG[p*3+1]=dy; relG[p*3+2]=dz;
}

// ---------------- per-layer transforms: q,k,v,skip ----------------
// block = 256 = 8 nodes x 32 lanes (lane = output channel o)
// output layout: [node][o*3+v]  (lane-contiguous float3 per channel)
__global__ __launch_bounds__(256) void k_transform(
    const float* __restrict__ x,
    const float* __restrict__ Wq, const float* __restrict__ Wk,
    const float* __restrict__ Wv, const float* __restrict__ Ws,
    float* __restrict__ q, float* __restrict__ k,
    float* __restrict__ v, float* __restrict__ s,
    int n, int Cin, int Cout){
  __shared__ float w4[4][1024];
  __shared__ float xr[8][96];
  int tid = threadIdx.x;
  int nw = Cin * Cout;
  for (int i = tid; i < nw; i += 256){
    w4[0][i] = Wq[i]; w4[1][i] = Wk[i]; w4[2][i] = Wv[i]; w4[3][i] = Ws[i];
  }
  int g = tid >> 5, lane = tid & 31;
  int node = blockIdx.x*8 + g;
  int xl = Cin * 3;
  if (node < n){
    for (int j = lane; j < xl; j += 32) xr[g][j] = x[node*xl + j];
  }
  __syncthreads();
  if (node < n && lane < Cout){
    int OV = Cout*3;
    #pragma unroll
    for (int vv = 0; vv < 3; ++vv){
      float aq=0.f, ak=0.f, av=0.f, as=0.f;
      for (int c = 0; c < Cin; ++c){
        float xv = xr[g][c*3+vv];
        aq += xv * w4[0][c*Cout+lane];
        ak += xv * w4[1][c*Cout+lane];
        av += xv * w4[2][c*Cout+lane];
        as += xv * w4[3][c*Cout+lane];
      }
      int o = node*OV + lane*3 + vv;
      q[o]=aq; k[o]=ak; v[o]=av; s[o]=as;
    }
  }
}

// ---------------- fused attention + skip + GNormBias ----------------
// lane = channel; each lane holds its channel's float3. No max-tracking
// (logits are O(1)), owner-lane rel accumulation, lane-local norm epilogue.
__global__ __launch_bounds__(256) void k_attn(
    const float* __restrict__ qb, const float* __restrict__ kb,
    const float* __restrict__ vb, const float* __restrict__ sb,
    const int* __restrict__ row, const int* __restrict__ srcs,
    const float* __restrict__ rG, const float* __restrict__ relG,
    const float* __restrict__ wr1, const float* __restrict__ wr2,
    const float* __restrict__ scaleA, const float* __restrict__ biasA,
    float* __restrict__ outb,
    int n, int Cout, float invsc){
  int tid = threadIdx.x, g = tid >> 5, lane = tid & 31;
  int node = blockIdx.x*8 + g;
  if (node >= n) return;
  int OV = Cout*3;
  bool ch = lane < Cout;
  float rw1 = (lane < 16) ? wr1[lane] : 0.f;
  float rw2 = (lane < 16) ? wr2[lane] : 0.f;
  int base = node*OV + 3*lane;
  float ql0=0.f, ql1=0.f, ql2=0.f;
  if (ch){ ql0 = qb[base]*invsc; ql1 = qb[base+1]*invsc; ql2 = qb[base+2]*invsc; }
  float z = 0.f, a0=0.f, a1=0.f, a2=0.f, R0=0.f, R1=0.f, R2=0.f;
  int beg = row[node], end = row[node+1];
  for (int cb = beg; cb < end; cb += 32){
    int csz = end - cb; if (csz > 32) csz = 32;
    // stage one edge per lane (coalesced, CSR-ordered payload)
    int sn_l = 0; float rr_l = 0.f, rx_l = 0.f, ry_l = 0.f, rz_l = 0.f;
    if (lane < csz){
      int idx = cb + lane;
      sn_l = srcs[idx];
      rr_l = rG[idx];
      rx_l = relG[idx*3+0]; ry_l = relG[idx*3+1]; rz_l = relG[idx*3+2];
    }
    for (int j = 0; j < csz; j += 4){
      int gs = csz - j; if (gs > 4) gs = 4;
      int sid[4]; float rrB[4];
      #pragma unroll
      for (int t = 0; t < 4; ++t){
        int sl = (j + t) & 31;
        sid[t] = __shfl(sn_l, sl, 32);
        rrB[t] = __shfl(rr_l, sl, 32);
      }
      // batched contiguous float3 gathers (k & v) for the group
      float kf[4][3], vf[4][3];
      #pragma unroll
      for (int t = 0; t < 4; ++t){
        const float* kp = kb + sid[t]*OV + 3*lane;
        const float* vp = vb + sid[t]*OV + 3*lane;
        bool ok = ch && (t < gs);
        kf[t][0] = ok ? kp[0] : 0.f; kf[t][1] = ok ? kp[1] : 0.f; kf[t][2] = ok ? kp[2] : 0.f;
        vf[t][0] = ok ? vp[0] : 0.f; vf[t][1] = ok ? vp[1] : 0.f; vf[t][2] = ok ? vp[2] : 0.f;
      }
      // 4 logits; radial bias folded pre-butterfly (lanes 0..15)
      float w4[4];
      #pragma unroll
      for (int t = 0; t < 4; ++t){
        float pt = kf[t][0]*ql0 + kf[t][1]*ql1 + kf[t][2]*ql2;
        pt += fmaxf(rrB[t]*rw1, 0.f) * rw2;
        #pragma unroll
        for (int off = 16; off; off >>= 1) pt += __shfl_xor(pt, off, 32);
        w4[t] = (t < gs) ? __expf(fminf(pt, 80.f)) : 0.f;
      }
      #pragma unroll
      for (int t = 0; t < 4; ++t){
        z  += w4[t];
        a0 += w4[t]*vf[t][0]; a1 += w4[t]*vf[t][1]; a2 += w4[t]*vf[t][2];
        if (lane == j + t){ R0 += w4[t]*rx_l; R1 += w4[t]*ry_l; R2 += w4[t]*rz_l; }
      }
    }
  }
  // rel-message term is channel-independent: one reduce per node
  #pragma unroll
  for (int off = 16; off; off >>= 1){
    R0 += __shfl_xor(R0, off, 32);
    R1 += __shfl_xor(R1, off, 32);
    R2 += __shfl_xor(R2, off, 32);
  }
  if (ch){
    float invz = 1.f / (z + EPS);
    float y0 = (a0 + R0)*invz + sb[base];
    float y1 = (a1 + R1)*invz + sb[base+1];
    float y2 = (a2 + R2)*invz + sb[base+2];
    float nrm = sqrtf(y0*y0 + y1*y1 + y2*y2 + 1e-12f);
    float f = fmaxf(scaleA[lane]*nrm + biasA[lane], 0.f) / nrm;
    outb[base]   = f*y0;
    outb[base+1] = f*y1;
    outb[base+2] = f*y2;
  }
}

// ---------------- pooling / upsample ----------------
__global__ void k_pool_add(const float* __restrict__ x, const int* __restrict__ cl,
                           float* sum, float* cnt, int n0){
  int t = blockIdx.x*256 + threadIdx.x;
  if (t < n0*96){
    int nn = t / 96, j = t - nn*96;
    int c = cl[nn];
    atomicAdd(&sum[c*96 + j], x[t]);
    if (j == 0) atomicAdd(&cnt[c], 1.f);
  }
}
__global__ void k_pool_div(const float* __restrict__ sum, const float* __restrict__ cnt,
                           float* __restrict__ out, int n1){
  int t = blockIdx.x*256 + threadIdx.x;
  if (t < n1*96) out[t] = sum[t] / (cnt[t/96] + EPS);
}
__global__ void k_scatter_add(const float* __restrict__ x, const int* __restrict__ idx,
                              float* out, int n2){
  int t = blockIdx.x*256 + threadIdx.x;
  if (t < n2*96){
    int nn = t / 96, j = t - nn*96;
    out[idx[nn]*96 + j] += x[t];   // idx is a permutation slice -> unique
  }
}

// ---------------- MLP head ----------------
__global__ void k_head(const float* __restrict__ x, const float* __restrict__ W,
                       float* __restrict__ out, int n){
  __shared__ float w[120];
  int tid = threadIdx.x;
  if (tid < 120) w[tid] = W[tid];
  __syncthreads();
  int idx = blockIdx.x*256 + tid;
  if (idx < n*40){
    int nn = idx / 40, o = idx - nn*40;
    float a = x[nn*3+0]*w[o] + x[nn*3+1]*w[40+o] + x[nn*3+2]*w[80+o];
    out[idx] = fmaxf(a, 0.f);
  }
}

extern "C" void kernel_launch(void* const* d_in, const int* in_sizes, int n_in,
                              void* d_out, int out_size, void* d_ws, size_t ws_size,
                              hipStream_t stream){
  // ---- inputs ----
  const float* pos0      = (const float*)d_in[0];
  const float* v0        = (const float*)d_in[1];
  const float* Wq_first  = (const float*)d_in[2];
  const float* Wk_first  = (const float*)d_in[3];
  const float* Wv_first  = (const float*)d_in[4];
  const float* Ws_first  = (const float*)d_in[5];
  const float* Wq_mid    = (const float*)d_in[6];
  const float* Wk_mid    = (const float*)d_in[7];
  const float* Wv_mid    = (const float*)d_in[8];
  const float* Ws_mid    = (const float*)d_in[9];
  const float* Wq_last   = (const float*)d_in[10];
  const float* Wk_last   = (const float*)d_in[11];
  const float* Wv_last   = (const float*)d_in[12];
  const float* Ws_last   = (const float*)d_in[13];
  const float* wr1       = (const float*)d_in[14];
  const float* wr2       = (const float*)d_in[15];
  const float* scale_mid = (const float*)d_in[16];
  const float* bias_mid  = (const float*)d_in[17];
  const float* scale_last= (const float*)d_in[18];
  const float* bias_last = (const float*)d_in[19];
  const float* Wmlp      = (const float*)d_in[20];
  const int* src0 = (const int*)d_in[21];
  const int* dst0 = (const int*)d_in[22];
  const int* src1 = (const int*)d_in[23];
  const int* dst1 = (const int*)d_in[24];
  const int* src2 = (const int*)d_in[25];
  const int* dst2 = (const int*)d_in[26];
  const int* fp1  = (const int*)d_in[27];
  const int* fp2  = (const int*)d_in[28];
  const int* cl1  = (const int*)d_in[29];
  const int* cl2  = (const int*)d_in[30];

  // ---- workspace layout (floats) ----
  float* ws = (float*)d_ws;
  size_t o = 0;
  float* xA   = ws + o; o += (size_t)N0*96;
  float* xB   = ws + o; o += (size_t)N0*96;
  float* x0s  = ws + o; o += (size_t)N0*96;
  float* x1s  = ws + o; o += (size_t)N1*96;
  float* qb   = ws + o; o += (size_t)N0*96;
  float* kb   = ws + o; o += (size_t)N0*96;
  float* vb   = ws + o; o += (size_t)N0*96;
  float* sb   = ws + o; o += (size_t)N0*96;
  float* pcnt = ws + o; o += N1;
  float* pos1 = ws + o; o += (size_t)N1*3;
  float* pos2 = ws + o; o += (size_t)N2*3;
  float* rGA  = ws + o; o += ETOT;
  float* relGA= ws + o; o += (size_t)ETOT*3;
  int* ib = (int*)(ws + o);
  size_t io = 0;
  int* rowA  = ib + io; io += NTOT+1;
  int* cntA  = ib + io; io += NTOT;
  int* curA  = ib + io; io += NTOT;
  int* exclA = ib + io; io += NTOT;
  int* bsumA = ib + io; io += 256;
  int* srcsA = ib + io; io += ETOT;

  // ---- pooled positions ----
  k_gather_pos<<<cdiv(N1,256),256,0,stream>>>(pos0, fp1, pos1, N1);
  k_gather_pos<<<cdiv(N2,256),256,0,stream>>>(pos1, fp2, pos2, N2);

  // ---- concatenated CSR build (one scan for all 3 levels) ----
  hipMemsetAsync(cntA, 0, NTOT*sizeof(int), stream);
  k_countA<<<cdiv(ETOT,256),256,0,stream>>>(dst0, dst1, dst2, cntA);
  k_scan1<<<NBLK,256,0,stream>>>(cntA, exclA, bsumA);
  k_scan2<<<1,256,0,stream>>>(bsumA, NBLK);
  k_scan3<<<NBLK,256,0,stream>>>(exclA, bsumA, rowA, curA);
  k_scatter_geoA<<<cdiv(ETOT,256),256,0,stream>>>(src0, dst0, src1, dst1, src2, dst2,
                                                  pos0, pos1, pos2, curA,
                                                  srcsA, rGA, relGA);

  // ---- layer driver ----
  auto layer = [&](const float* xin, int n, int nodeBase, int Cin, int Cout,
                   const float* Wq_, const float* Wk_, const float* Wv_, const float* Ws_,
                   int lidx, const float* scale_, const float* bias_, float* xout){
    k_transform<<<cdiv(n,8),256,0,stream>>>(xin, Wq_, Wk_, Wv_, Ws_, qb, kb, vb, sb, n, Cin, Cout);
    float invsc = 1.f / sqrtf(3.f * (float)Cout);
    k_attn<<<cdiv(n,8),256,0,stream>>>(qb, kb, vb, sb, rowA + nodeBase, srcsA, rGA, relGA,
                                       wr1 + lidx*16, wr2 + lidx*16, scale_, bias_,
                                       xout, n, Cout, invsc);
  };

  const int C = 32;
  // L0: v0 (Cin=1) -> xA ; L1 -> x0s
  layer(v0, N0, 0, 1, C, Wq_first, Wk_first, Wv_first, Ws_first,
        0, scale_mid + 0*C, bias_mid + 0*C, xA);
  layer(xA, N0, 0, C, C, Wq_mid+0*1024, Wk_mid+0*1024, Wv_mid+0*1024, Ws_mid+0*1024,
        1, scale_mid + 1*C, bias_mid + 1*C, x0s);
  // pool1: x0s -> xA(sums) -> xB
  hipMemsetAsync(xA, 0, (size_t)N1*96*sizeof(float), stream);
  hipMemsetAsync(pcnt, 0, N1*sizeof(float), stream);
  k_pool_add<<<cdiv(N0*96,256),256,0,stream>>>(x0s, cl1, xA, pcnt, N0);
  k_pool_div<<<cdiv(N1*96,256),256,0,stream>>>(xA, pcnt, xB, N1);
  // L2 -> xA, L3 -> x1s
  layer(xB, N1, N0, C, C, Wq_mid+1*1024, Wk_mid+1*1024, Wv_mid+1*1024, Ws_mid+1*1024,
        2, scale_mid + 2*C, bias_mid + 2*C, xA);
  layer(xA, N1, N0, C, C, Wq_mid+2*1024, Wk_mid+2*1024, Wv_mid+2*1024, Ws_mid+2*1024,
        3, scale_mid + 3*C, bias_mid + 3*C, x1s);
  // pool2: x1s -> xA(sums, N2) -> xB
  hipMemsetAsync(xA, 0, (size_t)N2*96*sizeof(float), stream);
  hipMemsetAsync(pcnt, 0, N2*sizeof(float), stream);
  k_pool_add<<<cdiv(N1*96,256),256,0,stream>>>(x1s, cl2, xA, pcnt, N1);
  k_pool_div<<<cdiv(N2*96,256),256,0,stream>>>(xA, pcnt, xB, N2);
  // L4 -> xA, L5 -> xB
  layer(xB, N2, N0+N1, C, C, Wq_mid+3*1024, Wk_mid+3*1024, Wv_mid+3*1024, Ws_mid+3*1024,
        4, scale_mid + 4*C, bias_mid + 4*C, xA);
  layer(xA, N2, N0+N1, C, C, Wq_mid+4*1024, Wk_mid+4*1024, Wv_mid+4*1024, Ws_mid+4*1024,
        5, scale_mid + 5*C, bias_mid + 5*C, xB);
  // upsample -> level 1: xA = x1s; xA[fp2] += xB
  hipMemcpyAsync(xA, x1s, (size_t)N1*96*sizeof(float), hipMemcpyDeviceToDevice, stream);
  k_scatter_add<<<cdiv(N2*96,256),256,0,stream>>>(xB, fp2, xA, N2);
  // L6 -> xB, L7 -> xA
  layer(xA, N1, N0, C, C, Wq_mid+5*1024, Wk_mid+5*1024, Wv_mid+5*1024, Ws_mid+5*1024,
        6, scale_mid + 6*C, bias_mid + 6*C, xB);
  layer(xB, N1, N0, C, C, Wq_mid+6*1024, Wk_mid+6*1024, Wv_mid+6*1024, Ws_mid+6*1024,
        7, scale_mid + 7*C, bias_mid + 7*C, xA);
  // upsample -> level 0: xB = x0s; xB[fp1] += xA
  hipMemcpyAsync(xB, x0s, (size_t)N0*96*sizeof(float), hipMemcpyDeviceToDevice, stream);
  k_scatter_add<<<cdiv(N1*96,256),256,0,stream>>>(xA, fp1, xB, N1);
  // L8 -> xA
  layer(xB, N0, 0, C, C, Wq_mid+7*1024, Wk_mid+7*1024, Wv_mid+7*1024, Ws_mid+7*1024,
        8, scale_mid + 8*C, bias_mid + 8*C, xA);
  // L9 (Cout=1) -> xB (N0*3)
  layer(xA, N0, 0, C, 1, Wq_last, Wk_last, Wv_last, Ws_last,
        9, scale_last, bias_last, xB);
  // head
  k_head<<<cdiv(N0*40,256),256,0,stream>>>(xB, Wmlp, (float*)d_out, N0);
}

// Round 5
// 585.454 us; speedup vs baseline: 1.2232x; 1.2232x over previous
//
#include <hip/hip_runtime.h>
#include <math.h>

#define N0 32768
#define N1 8192
#define N2 2048
#define E0 262144
#define E1 65536
#define E2 16384
#define NTOT (N0+N1+N2)     // 43008 (multiple of 256)
#define ETOT (E0+E1+E2)     // 344064
#define NBLK (NTOT/256)     // 168
#define EPS 1e-9f

static inline int cdiv(int a, int b){ return (a + b - 1) / b; }

// bf16 pack (RNE) / unpack helpers
__device__ inline unsigned bfpack(float a, float b){
  unsigned ua = __float_as_uint(a), ub = __float_as_uint(b);
  ua = (ua + 0x7fffu + ((ua >> 16) & 1u)) >> 16;
  ub = (ub + 0x7fffu + ((ub >> 16) & 1u)) & 0xffff0000u;
  return ua | ub;
}
__device__ inline float bf_lo(unsigned d){ return __uint_as_float(d << 16); }
__device__ inline float bf_hi(unsigned d){ return __uint_as_float(d & 0xffff0000u); }

// ---------------- small utility kernels ----------------
__global__ void k_gather_pos(const float* __restrict__ pos, const int* __restrict__ idx,
                             float* __restrict__ out, int n){
  int i = blockIdx.x*256 + threadIdx.x;
  if (i < n){
    int s = idx[i];
    out[i*3+0] = pos[s*3+0];
    out[i*3+1] = pos[s*3+1];
    out[i*3+2] = pos[s*3+2];
  }
}

// ---------------- concatenated CSR build ----------------
__global__ void k_countA(const int* __restrict__ d0, const int* __restrict__ d1,
                         const int* __restrict__ d2, int* cnt){
  int e = blockIdx.x*256 + threadIdx.x;
  if (e < E0)            atomicAdd(&cnt[d0[e]], 1);
  else if (e < E0+E1)    atomicAdd(&cnt[N0 + d1[e-E0]], 1);
  else if (e < ETOT)     atomicAdd(&cnt[N0+N1 + d2[e-E0-E1]], 1);
}
__global__ __launch_bounds__(256) void k_scan1(const int* __restrict__ cnt,
                                               int* __restrict__ excl,
                                               int* __restrict__ bsum){
  __shared__ int lds[256];
  int tid = threadIdx.x;
  int i = blockIdx.x*256 + tid;
  int v = cnt[i];
  lds[tid] = v;
  __syncthreads();
  for (int off = 1; off < 256; off <<= 1){
    int t = (tid >= off) ? lds[tid - off] : 0;
    __syncthreads();
    lds[tid] += t;
    __syncthreads();
  }
  excl[i] = lds[tid] - v;
  if (tid == 255) bsum[blockIdx.x] = lds[255];
}
__global__ __launch_bounds__(256) void k_scan2(int* bsum, int nb){
  __shared__ int lds[256];
  int tid = threadIdx.x;
  int v = (tid < nb) ? bsum[tid] : 0;
  lds[tid] = v;
  __syncthreads();
  for (int off = 1; off < 256; off <<= 1){
    int t = (tid >= off) ? lds[tid - off] : 0;
    __syncthreads();
    lds[tid] += t;
    __syncthreads();
  }
  if (tid < nb) bsum[tid] = lds[tid] - v;
}
__global__ __launch_bounds__(256) void k_scan3(const int* __restrict__ excl,
                                               const int* __restrict__ bsum,
                                               int* __restrict__ row,
                                               int* __restrict__ cur){
  int i = blockIdx.x*256 + threadIdx.x;
  int r = excl[i] + bsum[blockIdx.x];
  row[i] = r; cur[i] = r;
  if (i == 0) row[NTOT] = ETOT;
}
__global__ void k_scatter_geoA(const int* __restrict__ s0, const int* __restrict__ d0,
                               const int* __restrict__ s1, const int* __restrict__ d1,
                               const int* __restrict__ s2, const int* __restrict__ d2,
                               const float* __restrict__ pos0, const float* __restrict__ pos1,
                               const float* __restrict__ pos2, int* cur,
                               int* __restrict__ srcs, float* __restrict__ rG,
                               float* __restrict__ relG){
  int e = blockIdx.x*256 + threadIdx.x;
  if (e >= ETOT) return;
  int s, d, noff; const float* pos;
  if (e < E0)        { s = s0[e];        d = d0[e];        pos = pos0; noff = 0; }
  else if (e < E0+E1){ s = s1[e-E0];     d = d1[e-E0];     pos = pos1; noff = N0; }
  else               { s = s2[e-E0-E1];  d = d2[e-E0-E1];  pos = pos2; noff = N0+N1; }
  float dx = pos[d*3+0]-pos[s*3+0];
  float dy = pos[d*3+1]-pos[s*3+1];
  float dz = pos[d*3+2]-pos[s*3+2];
  int p = atomicAdd(&cur[noff + d], 1);
  srcs[p] = s;
  rG[p] = sqrtf(dx*dx+dy*dy+dz*dz+1e-12f);
  relG[p*3+0]=dx; relG[p*3+1]=dy; relG[p*3+2]=dz;
}

// ---------------- per-layer transforms: q, packed-kv (bf16), skip ----------------
// block = 256 = 8 nodes x 32 lanes (lane = output channel o)
// q,s: fp32 element order [node][c*3+v]. kv (pack=1): 96 dwords/node,
// dword j = bf16 pair (elem 2j, 2j+1) of concat [k(96)|v(96)].
__global__ __launch_bounds__(256) void k_transform(
    const float* __restrict__ x,
    const float* __restrict__ Wq, const float* __restrict__ Wk,
    const float* __restrict__ Wv, const float* __restrict__ Ws,
    float* __restrict__ q, unsigned* __restrict__ kv,
    float* __restrict__ kf32, float* __restrict__ vf32,
    float* __restrict__ s,
    int n, int Cin, int Cout, int pack){
  __shared__ float w4[4][1024];
  __shared__ float xr[8][96];
  __shared__ float kvst[8][192];
  int tid = threadIdx.x;
  int nw = Cin * Cout;
  for (int i = tid; i < nw; i += 256){
    w4[0][i] = Wq[i]; w4[1][i] = Wk[i]; w4[2][i] = Wv[i]; w4[3][i] = Ws[i];
  }
  int g = tid >> 5, lane = tid & 31;
  int node = blockIdx.x*8 + g;
  int xl = Cin * 3;
  if (node < n){
    for (int j = lane; j < xl; j += 32) xr[g][j] = x[node*xl + j];
  }
  __syncthreads();
  if (node < n && lane < Cout){
    int OV = Cout*3;
    #pragma unroll
    for (int vv = 0; vv < 3; ++vv){
      float aq=0.f, ak=0.f, av=0.f, as=0.f;
      for (int c = 0; c < Cin; ++c){
        float xv = xr[g][c*3+vv];
        aq += xv * w4[0][c*Cout+lane];
        ak += xv * w4[1][c*Cout+lane];
        av += xv * w4[2][c*Cout+lane];
        as += xv * w4[3][c*Cout+lane];
      }
      int o = node*OV + lane*3 + vv;
      q[o]=aq; s[o]=as;
      if (pack){
        kvst[g][lane*3+vv] = ak;
        kvst[g][96 + lane*3+vv] = av;
      } else {
        kf32[o]=ak; vf32[o]=av;
      }
    }
  }
  if (pack){
    __syncthreads();
    if (node < n){
      #pragma unroll
      for (int t = 0; t < 3; ++t){
        int j = lane + 32*t;
        kv[node*96 + j] = bfpack(kvst[g][2*j], kvst[g][2*j+1]);
      }
    }
  }
}

// ---------------- fused attention (Cout=32, packed bf16 kv) ----------------
__global__ __launch_bounds__(256) void k_attn32(
    const float* __restrict__ qb, const unsigned* __restrict__ kvb,
    const float* __restrict__ sb,
    const int* __restrict__ row, const int* __restrict__ srcs,
    const float* __restrict__ rG, const float* __restrict__ relG,
    const float* __restrict__ wr1, const float* __restrict__ wr2,
    const float* __restrict__ scaleA, const float* __restrict__ biasA,
    float* __restrict__ outb, int n, float invsc){
  __shared__ float vsum[8][96];
  int tid = threadIdx.x, g = tid >> 5, lane = tid & 31;
  int node = blockIdx.x*8 + g;
  bool act = node < n;
  float rw1 = (lane < 16) ? wr1[lane] : 0.f;
  float rw2 = (lane < 16) ? wr2[lane] : 0.f;
  float ql0=0.f, ql1=0.f, ql2=0.f, ql3=0.f;
  float z=0.f, av0=0.f, av1=0.f, av2=0.f, av3=0.f, R0=0.f, R1=0.f, R2=0.f;
  int beg=0, end=0;
  if (act){
    int nb = node*96;
    ql0 = qb[nb + 2*lane]*invsc;  ql1 = qb[nb + 2*lane+1]*invsc;
    if (lane < 16){ ql2 = qb[nb + 64 + 2*lane]*invsc; ql3 = qb[nb + 65 + 2*lane]*invsc; }
    beg = row[node]; end = row[node+1];
  }
  for (int cb = beg; cb < end; cb += 32){
    int csz = end - cb; if (csz > 32) csz = 32;
    int sn_l = 0; float rr_l = 0.f, rx_l = 0.f, ry_l = 0.f, rz_l = 0.f;
    if (lane < csz){
      int idx = cb + lane;
      sn_l = srcs[idx];
      rr_l = rG[idx];
      rx_l = relG[idx*3+0]; ry_l = relG[idx*3+1]; rz_l = relG[idx*3+2];
    }
    for (int j = 0; j < csz; j += 4){
      int gs = csz - j; if (gs > 4) gs = 4;
      int sid[4]; float rrB[4];
      #pragma unroll
      for (int t = 0; t < 4; ++t){
        int sl = (j + t) & 31;
        sid[t] = __shfl(sn_l, sl, 32);
        rrB[t] = __shfl(rr_l, sl, 32);
      }
      // 12 independent lane-coalesced dword gathers per group (MLP!)
      unsigned d0[4], d1[4], d2[4];
      #pragma unroll
      for (int t = 0; t < 4; ++t){
        const unsigned* kp = kvb + (size_t)sid[t]*96;
        bool ok = t < gs;
        d0[t] = ok ? kp[lane]      : 0u;
        d1[t] = ok ? kp[lane+32]   : 0u;
        d2[t] = ok ? kp[lane+64]   : 0u;
      }
      #pragma unroll
      for (int t = 0; t < 4; ++t){
        float pt = bf_lo(d0[t])*ql0 + bf_hi(d0[t])*ql1;
        if (lane < 16) pt += bf_lo(d1[t])*ql2 + bf_hi(d1[t])*ql3;
        pt += fmaxf(rrB[t]*rw1, 0.f) * rw2;
        #pragma unroll
        for (int off = 16; off; off >>= 1) pt += __shfl_xor(pt, off, 32);
        float w = (t < gs) ? __expf(fminf(pt, 80.f)) : 0.f;
        z += w;
        av0 += w*bf_lo(d2[t]); av1 += w*bf_hi(d2[t]);
        if (lane >= 16){ av2 += w*bf_lo(d1[t]); av3 += w*bf_hi(d1[t]); }
        if (lane == j + t){ R0 += w*rx_l; R1 += w*ry_l; R2 += w*rz_l; }
      }
    }
  }
  #pragma unroll
  for (int off = 16; off; off >>= 1){
    R0 += __shfl_xor(R0, off, 32);
    R1 += __shfl_xor(R1, off, 32);
    R2 += __shfl_xor(R2, off, 32);
  }
  if (act){
    vsum[g][2*lane+32] = av0;
    vsum[g][2*lane+33] = av1;
    if (lane >= 16){ vsum[g][2*lane-32] = av2; vsum[g][2*lane-31] = av3; }
  }
  __syncthreads();
  if (act){
    float invz = 1.f / (z + EPS);
    int base = node*96 + 3*lane;
    float y0 = (vsum[g][3*lane+0] + R0)*invz + sb[base];
    float y1 = (vsum[g][3*lane+1] + R1)*invz + sb[base+1];
    float y2 = (vsum[g][3*lane+2] + R2)*invz + sb[base+2];
    float nrm = sqrtf(y0*y0 + y1*y1 + y2*y2 + 1e-12f);
    float f = fmaxf(scaleA[lane]*nrm + biasA[lane], 0.f) / nrm;
    outb[base]   = f*y0;
    outb[base+1] = f*y1;
    outb[base+2] = f*y2;
  }
}

// ---------------- generic fp32 attention (used for Cout=1 last layer) ----------------
__global__ __launch_bounds__(256) void k_attn_g(
    const float* __restrict__ qb, const float* __restrict__ kb,
    const float* __restrict__ vb, const float* __restrict__ sb,
    const int* __restrict__ row, const int* __restrict__ srcs,
    const float* __restrict__ rG, const float* __restrict__ relG,
    const float* __restrict__ wr1, const float* __restrict__ wr2,
    const float* __restrict__ scaleA, const float* __restrict__ biasA,
    float* __restrict__ outb,
    int n, int Cout, float invsc){
  __shared__ float snorm[8][96];
  int tid = threadIdx.x, g = tid >> 5, lane = tid & 31;
  int node = blockIdx.x*8 + g;
  int OV = Cout*3;
  bool act = node < n;
  int jj[3], vc[3];
  #pragma unroll
  for (int kk = 0; kk < 3; ++kk){ jj[kk] = lane + 32*kk; vc[kk] = jj[kk] % 3; }
  float rw1 = (lane < 16) ? wr1[lane] : 0.f;
  float rw2 = (lane < 16) ? wr2[lane] : 0.f;
  if (act){
    int base = node*OV;
    float ql[3];
    #pragma unroll
    for (int kk = 0; kk < 3; ++kk)
      ql[kk] = (jj[kk] < OV) ? qb[base + jj[kk]] * invsc : 0.f;
    float z = 0.f;
    float acc[3] = {0.f, 0.f, 0.f};
    int beg = row[node], end = row[node+1];
    for (int cb = beg; cb < end; cb += 32){
      int csz = end - cb; if (csz > 32) csz = 32;
      int sn_l = 0; float rr_l = 0.f, rx_l = 0.f, ry_l = 0.f, rz_l = 0.f;
      if (lane < csz){
        int idx = cb + lane;
        sn_l = srcs[idx];
        rr_l = rG[idx];
        rx_l = relG[idx*3+0]; ry_l = relG[idx*3+1]; rz_l = relG[idx*3+2];
      }
      for (int j = 0; j < csz; j += 4){
        int gs = csz - j; if (gs > 4) gs = 4;
        int sid[4]; float rrB[4], rxt[4], ryt[4], rzt[4];
        #pragma unroll
        for (int t = 0; t < 4; ++t){
          int sl = (j + t) & 31;
          sid[t] = __shfl(sn_l, sl, 32);
          rrB[t] = __shfl(rr_l, sl, 32);
          rxt[t] = __shfl(rx_l, sl, 32);
          ryt[t] = __shfl(ry_l, sl, 32);
          rzt[t] = __shfl(rz_l, sl, 32);
        }
        float kf[4][3], vf[4][3];
        #pragma unroll
        for (int t = 0; t < 4; ++t){
          int kbase = sid[t]*OV;
          #pragma unroll
          for (int kk = 0; kk < 3; ++kk){
            bool ok = (t < gs) && (jj[kk] < OV);
            kf[t][kk] = ok ? kb[kbase + jj[kk]] : 0.f;
            vf[t][kk] = ok ? vb[kbase + jj[kk]] : 0.f;
          }
        }
        #pragma unroll
        for (int t = 0; t < 4; ++t){
          float pt = kf[t][0]*ql[0] + kf[t][1]*ql[1] + kf[t][2]*ql[2];
          pt += fmaxf(rrB[t]*rw1, 0.f) * rw2;
          #pragma unroll
          for (int off = 16; off; off >>= 1) pt += __shfl_xor(pt, off, 32);
          float w = (t < gs) ? __expf(fminf(pt, 80.f)) : 0.f;
          z += w;
          float rc[3] = {rxt[t], ryt[t], rzt[t]};
          #pragma unroll
          for (int kk = 0; kk < 3; ++kk)
            acc[kk] += w*(vf[t][kk] + rc[vc[kk]]);
        }
      }
    }
    float invz = 1.f / (z + EPS);
    #pragma unroll
    for (int kk = 0; kk < 3; ++kk)
      if (jj[kk] < OV)
        snorm[g][jj[kk]] = acc[kk]*invz + sb[base + jj[kk]];
  }
  __syncthreads();
  if (act && lane < Cout){
    float a = snorm[g][3*lane+0];
    float b = snorm[g][3*lane+1];
    float c = snorm[g][3*lane+2];
    float nrm = sqrtf(a*a + b*b + c*c + 1e-12f);
    float f = fmaxf(scaleA[lane]*nrm + biasA[lane], 0.f) / nrm;
    int base = node*OV + 3*lane;
    outb[base+0] = f*a; outb[base+1] = f*b; outb[base+2] = f*c;
  }
}

// ---------------- pooling / upsample ----------------
__global__ void k_pool_add(const float* __restrict__ x, const int* __restrict__ cl,
                           float* sum, float* cnt, int n0){
  int t = blockIdx.x*256 + threadIdx.x;
  if (t < n0*96){
    int nn = t / 96, j = t - nn*96;
    int c = cl[nn];
    atomicAdd(&sum[c*96 + j], x[t]);
    if (j == 0) atomicAdd(&cnt[c], 1.f);
  }
}
__global__ void k_pool_div(const float* __restrict__ sum, const float* __restrict__ cnt,
                           float* __restrict__ out, int n1){
  int t = blockIdx.x*256 + threadIdx.x;
  if (t < n1*96) out[t] = sum[t] / (cnt[t/96] + EPS);
}
__global__ void k_scatter_add(const float* __restrict__ x, const int* __restrict__ idx,
                              float* out, int n2){
  int t = blockIdx.x*256 + threadIdx.x;
  if (t < n2*96){
    int nn = t / 96, j = t - nn*96;
    out[idx[nn]*96 + j] += x[t];
  }
}

// ---------------- MLP head ----------------
__global__ void k_head(const float* __restrict__ x, const float* __restrict__ W,
                       float* __restrict__ out, int n){
  __shared__ float w[120];
  int tid = threadIdx.x;
  if (tid < 120) w[tid] = W[tid];
  __syncthreads();
  int idx = blockIdx.x*256 + tid;
  if (idx < n*40){
    int nn = idx / 40, o = idx - nn*40;
    float a = x[nn*3+0]*w[o] + x[nn*3+1]*w[40+o] + x[nn*3+2]*w[80+o];
    out[idx] = fmaxf(a, 0.f);
  }
}

extern "C" void kernel_launch(void* const* d_in, const int* in_sizes, int n_in,
                              void* d_out, int out_size, void* d_ws, size_t ws_size,
                              hipStream_t stream){
  const float* pos0      = (const float*)d_in[0];
  const float* v0        = (const float*)d_in[1];
  const float* Wq_first  = (const float*)d_in[2];
  const float* Wk_first  = (const float*)d_in[3];
  const float* Wv_first  = (const float*)d_in[4];
  const float* Ws_first  = (const float*)d_in[5];
  const float* Wq_mid    = (const float*)d_in[6];
  const float* Wk_mid    = (const float*)d_in[7];
  const float* Wv_mid    = (const float*)d_in[8];
  const float* Ws_mid    = (const float*)d_in[9];
  const float* Wq_last   = (const float*)d_in[10];
  const float* Wk_last   = (const float*)d_in[11];
  const float* Wv_last   = (const float*)d_in[12];
  const float* Ws_last   = (const float*)d_in[13];
  const float* wr1       = (const float*)d_in[14];
  const float* wr2       = (const float*)d_in[15];
  const float* scale_mid = (const float*)d_in[16];
  const float* bias_mid  = (const float*)d_in[17];
  const float* scale_last= (const float*)d_in[18];
  const float* bias_last = (const float*)d_in[19];
  const float* Wmlp      = (const float*)d_in[20];
  const int* src0 = (const int*)d_in[21];
  const int* dst0 = (const int*)d_in[22];
  const int* src1 = (const int*)d_in[23];
  const int* dst1 = (const int*)d_in[24];
  const int* src2 = (const int*)d_in[25];
  const int* dst2 = (const int*)d_in[26];
  const int* fp1  = (const int*)d_in[27];
  const int* fp2  = (const int*)d_in[28];
  const int* cl1  = (const int*)d_in[29];
  const int* cl2  = (const int*)d_in[30];

  float* ws = (float*)d_ws;
  size_t o = 0;
  float* xA   = ws + o; o += (size_t)N0*96;
  float* xB   = ws + o; o += (size_t)N0*96;
  float* x0s  = ws + o; o += (size_t)N0*96;
  float* x1s  = ws + o; o += (size_t)N1*96;
  float* qb   = ws + o; o += (size_t)N0*96;
  float* sb   = ws + o; o += (size_t)N0*96;
  unsigned* kvb = (unsigned*)(ws + o); o += (size_t)N0*96;
  float* kbf  = ws + o; o += (size_t)N0*3;
  float* vbf  = ws + o; o += (size_t)N0*3;
  float* pcnt = ws + o; o += N1;
  float* pos1 = ws + o; o += (size_t)N1*3;
  float* pos2 = ws + o; o += (size_t)N2*3;
  float* rGA  = ws + o; o += ETOT;
  float* relGA= ws + o; o += (size_t)ETOT*3;
  int* ib = (int*)(ws + o);
  size_t io = 0;
  int* rowA  = ib + io; io += NTOT+1;
  int* cntA  = ib + io; io += NTOT;
  int* curA  = ib + io; io += NTOT;
  int* exclA = ib + io; io += NTOT;
  int* bsumA = ib + io; io += 256;
  int* srcsA = ib + io; io += ETOT;

  k_gather_pos<<<cdiv(N1,256),256,0,stream>>>(pos0, fp1, pos1, N1);
  k_gather_pos<<<cdiv(N2,256),256,0,stream>>>(pos1, fp2, pos2, N2);

  hipMemsetAsync(cntA, 0, NTOT*sizeof(int), stream);
  k_countA<<<cdiv(ETOT,256),256,0,stream>>>(dst0, dst1, dst2, cntA);
  k_scan1<<<NBLK,256,0,stream>>>(cntA, exclA, bsumA);
  k_scan2<<<1,256,0,stream>>>(bsumA, NBLK);
  k_scan3<<<NBLK,256,0,stream>>>(exclA, bsumA, rowA, curA);
  k_scatter_geoA<<<cdiv(ETOT,256),256,0,stream>>>(src0, dst0, src1, dst1, src2, dst2,
                                                  pos0, pos1, pos2, curA,
                                                  srcsA, rGA, relGA);

  // Cout=32 layer: packed bf16 kv path
  auto layer32 = [&](const float* xin, int n, int nodeBase, int Cin,
                     const float* Wq_, const float* Wk_, const float* Wv_, const float* Ws_,
                     int lidx, const float* scale_, const float* bias_, float* xout){
    k_transform<<<cdiv(n,8),256,0,stream>>>(xin, Wq_, Wk_, Wv_, Ws_,
                                            qb, kvb, kbf, vbf, sb, n, Cin, 32, 1);
    float invsc = 1.f / sqrtf(96.f);
    k_attn32<<<cdiv(n,8),256,0,stream>>>(qb, kvb, sb, rowA + nodeBase, srcsA, rGA, relGA,
                                         wr1 + lidx*16, wr2 + lidx*16, scale_, bias_,
                                         xout, n, invsc);
  };

  const int C = 32;
  layer32(v0, N0, 0, 1, Wq_first, Wk_first, Wv_first, Ws_first,
          0, scale_mid + 0*C, bias_mid + 0*C, xA);
  layer32(xA, N0, 0, C, Wq_mid+0*1024, Wk_mid+0*1024, Wv_mid+0*1024, Ws_mid+0*1024,
          1, scale_mid + 1*C, bias_mid + 1*C, x0s);
  hipMemsetAsync(xA, 0, (size_t)N1*96*sizeof(float), stream);
  hipMemsetAsync(pcnt, 0, N1*sizeof(float), stream);
  k_pool_add<<<cdiv(N0*96,256),256,0,stream>>>(x0s, cl1, xA, pcnt, N0);
  k_pool_div<<<cdiv(N1*96,256),256,0,stream>>>(xA, pcnt, xB, N1);
  layer32(xB, N1, N0, C, Wq_mid+1*1024, Wk_mid+1*1024, Wv_mid+1*1024, Ws_mid+1*1024,
          2, scale_mid + 2*C, bias_mid + 2*C, xA);
  layer32(xA, N1, N0, C, Wq_mid+2*1024, Wk_mid+2*1024, Wv_mid+2*1024, Ws_mid+2*1024,
          3, scale_mid + 3*C, bias_mid + 3*C, x1s);
  hipMemsetAsync(xA, 0, (size_t)N2*96*sizeof(float), stream);
  hipMemsetAsync(pcnt, 0, N2*sizeof(float), stream);
  k_pool_add<<<cdiv(N1*96,256),256,0,stream>>>(x1s, cl2, xA, pcnt, N1);
  k_pool_div<<<cdiv(N2*96,256),256,0,stream>>>(xA, pcnt, xB, N2);
  layer32(xB, N2, N0+N1, C, Wq_mid+3*1024, Wk_mid+3*1024, Wv_mid+3*1024, Ws_mid+3*1024,
          4, scale_mid + 4*C, bias_mid + 4*C, xA);
  layer32(xA, N2, N0+N1, C, Wq_mid+4*1024, Wk_mid+4*1024, Wv_mid+4*1024, Ws_mid+4*1024,
          5, scale_mid + 5*C, bias_mid + 5*C, xB);
  hipMemcpyAsync(xA, x1s, (size_t)N1*96*sizeof(float), hipMemcpyDeviceToDevice, stream);
  k_scatter_add<<<cdiv(N2*96,256),256,0,stream>>>(xB, fp2, xA, N2);
  layer32(xA, N1, N0, C, Wq_mid+5*1024, Wk_mid+5*1024, Wv_mid+5*1024, Ws_mid+5*1024,
          6, scale_mid + 6*C, bias_mid + 6*C, xB);
  layer32(xB, N1, N0, C, Wq_mid+6*1024, Wk_mid+6*1024, Wv_mid+6*1024, Ws_mid+6*1024,
          7, scale_mid + 7*C, bias_mid + 7*C, xA);
  hipMemcpyAsync(xB, x0s, (size_t)N0*96*sizeof(float), hipMemcpyDeviceToDevice, stream);
  k_scatter_add<<<cdiv(N1*96,256),256,0,stream>>>(xA, fp1, xB, N1);
  layer32(xB, N0, 0, C, Wq_mid+7*1024, Wk_mid+7*1024, Wv_mid+7*1024, Ws_mid+7*1024,
          8, scale_mid + 8*C, bias_mid + 8*C, xA);
  // L9 (Cout=1): generic fp32 path
  k_transform<<<cdiv(N0,8),256,0,stream>>>(xA, Wq_last, Wk_last, Wv_last, Ws_last,
                                           qb, kvb, kbf, vbf, sb, N0, C, 1, 0);
  {
    float invsc = 1.f / sqrtf(3.f);
    k_attn_g<<<cdiv(N0,8),256,0,stream>>>(qb, kbf, vbf, sb, rowA + 0, srcsA, rGA, relGA,
                                          wr1 + 9*16, wr2 + 9*16, scale_last, bias_last,
                                          xB, N0, 1, invsc);
  }
  k_head<<<cdiv(N0*40,256),256,0,stream>>>(xB, Wmlp, (float*)d_out, N0);
}